// Round 2
// 495.253 us; speedup vs baseline: 1.0048x; 1.0048x over previous
//
#include <hip/hip_runtime.h>

// Problem constants (from reference setup_inputs)
#define BATCH 4
#define PTS   100000
#define CH    64
#define NPIX  (512 * 512)   // 262144 pixels per plane

// The network is fully linear:
//   out[b,p,o] = sum_c Ag[o][c]*grid[b,c,pillar] + sum_c Ap[o][c]*pc[b,p,c] + bias2[o]
// where A = Zw @ Yw (3x128), Ag = A[:, :64], Ap = A[:, 64:], bias2 = Zw@Yb + Zb.
//
// Two stream-ordered kernels (dispatch boundary = the only HW-reliable
// cross-XCD release/acquire on gfx950 — fused grid.sync raced, round 1):
//   K1: per-block fold Ag into LDS, then dense coalesced grid-reduce
//       -> G3[b,pix] = Ag @ grid[b,:,pix]   (16.8 MB table in ws)
//   K2: per-block fold Ap+bias into LDS, then per point:
//       16 B G3 gather + pc dot + store
//
// Workspace: [0) float4 G3[B*NPIX]  (16.8 MB)

// ---- K1: G3[b,pix,:] = Ag @ grid[b,:,pix]  (dense, coalesced) ----
__global__ __launch_bounds__(256) void grid_reduce_kernel(
    const float* __restrict__ grid,  // (B, 64, NPIX)
    const float* __restrict__ Yw,    // (32,128)
    const float* __restrict__ Zw,    // (3,32)
    float* __restrict__ ws)
{
    __shared__ float4 sAg[64];
    const int tid = threadIdx.x;

    // fold Ag column tid: A[o][tid] = sum_k Zw[o][k] * Yw[k][tid]
    if (tid < 64) {
        float a0 = 0.f, a1 = 0.f, a2 = 0.f;
#pragma unroll
        for (int k = 0; k < 32; ++k) {
            const float y = Yw[k * 128 + tid];   // coalesced, L2-hit after block 0
            a0 += Zw[k]      * y;
            a1 += Zw[32 + k] * y;
            a2 += Zw[64 + k] * y;
        }
        sAg[tid] = make_float4(a0, a1, a2, 0.f);
    }
    __syncthreads();

    // blockIdx.x in [0, B*256): b = blockIdx.x >> 8
    const int b   = blockIdx.x >> 8;
    const int grp = ((blockIdx.x & 255) << 8) | tid;  // 0..65535: float4 group
    const size_t pix0 = (size_t)grp * 4;

    const float* gbase = grid + (size_t)b * CH * NPIX + pix0;

    float4 acc0 = make_float4(0.f, 0.f, 0.f, 0.f);  // output ch 0, 4 pixels
    float4 acc1 = acc0;                              // output ch 1
    float4 acc2 = acc0;                              // output ch 2
#pragma unroll 8
    for (int c = 0; c < CH; ++c) {
        const float4 g = *(const float4*)(gbase + (size_t)c * NPIX);
        const float4 a = sAg[c];
        acc0.x += g.x * a.x; acc0.y += g.y * a.x; acc0.z += g.z * a.x; acc0.w += g.w * a.x;
        acc1.x += g.x * a.y; acc1.y += g.y * a.y; acc1.z += g.z * a.y; acc1.w += g.w * a.y;
        acc2.x += g.x * a.z; acc2.y += g.y * a.z; acc2.z += g.z * a.z; acc2.w += g.w * a.z;
    }

    float4* out4 = (float4*)ws + ((size_t)b * NPIX + pix0);
    out4[0] = make_float4(acc0.x, acc1.x, acc2.x, 0.f);
    out4[1] = make_float4(acc0.y, acc1.y, acc2.y, 0.f);
    out4[2] = make_float4(acc0.z, acc1.z, acc2.z, 0.f);
    out4[3] = make_float4(acc0.w, acc1.w, acc2.w, 0.f);
}

// ---- K2: per point: gather G3 (16 B) + pc dot + store ----
__global__ __launch_bounds__(256) void point_kernel(
    const float* __restrict__ pc,    // (B, P, 64)
    const int*   __restrict__ idx,   // (B, P, 64) broadcast along C
    const float* __restrict__ Yw,    // (32,128)
    const float* __restrict__ Yb,    // (32)
    const float* __restrict__ Zw,    // (3,32)
    const float* __restrict__ Zb,    // (3)
    const float* __restrict__ ws,
    float* __restrict__ out)         // (B, P, 3)
{
    __shared__ float4 sAp[64];
    __shared__ float4 sBias;
    const int tid = threadIdx.x;

    // fold Ap column tid: A[o][64+tid] = sum_k Zw[o][k] * Yw[k][64+tid]
    if (tid < 64) {
        float a0 = 0.f, a1 = 0.f, a2 = 0.f;
#pragma unroll
        for (int k = 0; k < 32; ++k) {
            const float y = Yw[k * 128 + 64 + tid];
            a0 += Zw[k]      * y;
            a1 += Zw[32 + k] * y;
            a2 += Zw[64 + k] * y;
        }
        sAp[tid] = make_float4(a0, a1, a2, 0.f);
    } else if (tid == 64) {
        float b0 = Zb[0], b1 = Zb[1], b2 = Zb[2];
        for (int k = 0; k < 32; ++k) {
            const float y = Yb[k];
            b0 += Zw[k]      * y;
            b1 += Zw[32 + k] * y;
            b2 += Zw[64 + k] * y;
        }
        sBias = make_float4(b0, b1, b2, 0.f);
    }
    __syncthreads();

    const long long g = (long long)blockIdx.x * 256 + tid;
    if (g >= (long long)BATCH * PTS) return;
    const int b = (int)(g / PTS);

    const int pillar = idx[(size_t)g * CH];
    const float4 gcell = ((const float4*)ws)[(size_t)b * NPIX + pillar];

    float z0 = gcell.x + sBias.x;
    float z1 = gcell.y + sBias.y;
    float z2 = gcell.z + sBias.z;

    const float4* pb = (const float4*)(pc + (size_t)g * CH);
#pragma unroll
    for (int c4 = 0; c4 < 16; ++c4) {
        const float4 x  = pb[c4];
        const float4 a0 = sAp[c4 * 4 + 0];
        const float4 a1 = sAp[c4 * 4 + 1];
        const float4 a2 = sAp[c4 * 4 + 2];
        const float4 a3 = sAp[c4 * 4 + 3];
        z0 += x.x * a0.x + x.y * a1.x + x.z * a2.x + x.w * a3.x;
        z1 += x.x * a0.y + x.y * a1.y + x.z * a2.y + x.w * a3.y;
        z2 += x.x * a0.z + x.y * a1.z + x.z * a2.z + x.w * a3.z;
    }

    float* op = out + (size_t)g * 3;
    op[0] = z0;
    op[1] = z1;
    op[2] = z2;
}

extern "C" void kernel_launch(void* const* d_in, const int* in_sizes, int n_in,
                              void* d_out, int out_size, void* d_ws, size_t ws_size,
                              hipStream_t stream) {
    const float* grid = (const float*)d_in[0];
    const float* pc   = (const float*)d_in[1];
    const int*   idx  = (const int*)d_in[2];
    const float* Yw   = (const float*)d_in[3];
    const float* Yb   = (const float*)d_in[4];
    const float* Zw   = (const float*)d_in[5];
    const float* Zb   = (const float*)d_in[6];
    float* out = (float*)d_out;
    float* ws  = (float*)d_ws;

    // B * NPIX/4 threads = 262144 -> 1024 blocks of 256 (256 blocks per batch)
    hipLaunchKernelGGL(grid_reduce_kernel, dim3(BATCH * 256), dim3(256), 0, stream,
                       grid, Yw, Zw, ws);

    const int total = BATCH * PTS;           // 400000
    const int blocks = (total + 255) / 256;  // 1563
    hipLaunchKernelGGL(point_kernel, dim3(blocks), dim3(256), 0, stream,
                       pc, idx, Yw, Yb, Zw, Zb, ws, out);
}